// Round 7
// baseline (622.685 us; speedup 1.0000x reference)
//
#include <hip/hip_runtime.h>
#include <hip/hip_bf16.h>
#include <stdint.h>

#define B_ 8
#define N_ 4096
#define T_ 512
#define M_ 4096
#define KVB 32
#define NBLK 64
#define NT 128            // M_/KVB
#define KT_F16 (KVB*T_)   // 16384 f16 = 32KB per K tile
#define VT_F16 (T_*KVB)   // 16384 f16 = 32KB per V tile

typedef _Float16 f16;
typedef __attribute__((ext_vector_type(8))) f16 f16x8;
typedef __attribute__((ext_vector_type(4))) f16 f16x4;
typedef __attribute__((ext_vector_type(4))) float f32x4;

__device__ __forceinline__ void gld16(const void* g, void* l) {
  __builtin_amdgcn_global_load_lds(
      (const __attribute__((address_space(1))) unsigned int*)g,
      (__attribute__((address_space(3))) unsigned int*)l, 16, 0, 0);
}

// ---------------- pack kernels (identical to R3/R6, proven) ----------------
__global__ __launch_bounds__(256) void pack_k(const float* __restrict__ Kg,
                                              f16* __restrict__ pk) {
  const int bx = blockIdx.x;
  const int ts = bx & 7;            // 64-t slab
  const int mt = (bx >> 3) & (NT - 1);
  const int b  = bx >> 10;
  const int m0 = mt * KVB;
  const int tid = threadIdx.x;
  __shared__ float tileT[64][33];
  {
    const int tl = tid >> 2;
    const int mseg = (tid & 3) * 8;
    const float* src = Kg + (size_t)(b * T_ + ts * 64 + tl) * M_ + m0 + mseg;
    const float4 a = *reinterpret_cast<const float4*>(src);
    const float4 c = *reinterpret_cast<const float4*>(src + 4);
    tileT[tl][mseg + 0] = a.x; tileT[tl][mseg + 1] = a.y;
    tileT[tl][mseg + 2] = a.z; tileT[tl][mseg + 3] = a.w;
    tileT[tl][mseg + 4] = c.x; tileT[tl][mseg + 5] = c.y;
    tileT[tl][mseg + 6] = c.z; tileT[tl][mseg + 7] = c.w;
  }
  __syncthreads();
  {
    const int m  = tid >> 3;
    const int jl = tid & 7;
    const int tlc = (jl ^ (m & 7)) * 8;
    f16x8 o;
    #pragma unroll
    for (int i = 0; i < 8; ++i) o[i] = (f16)tileT[tlc + i][m];
    f16* dst = pk + ((size_t)(b * NT + mt) * KVB + m) * T_ + (ts * 8 + jl) * 8;
    *reinterpret_cast<f16x8*>(dst) = o;
  }
}

__global__ __launch_bounds__(256) void pack_v(const float* __restrict__ Vg,
                                              f16* __restrict__ pv) {
  const int bx = blockIdx.x;        // b*NT + mt
  const int mt = bx & (NT - 1);
  const int b  = bx >> 7;
  const int m0 = mt * KVB;
  const int tid = threadIdx.x;
  #pragma unroll
  for (int r = 0; r < 8; ++r) {
    const int task = r * 256 + tid;
    const int t = task >> 2;
    const int c = task & 3;
    const int mc = (c ^ ((t >> 1) & 3)) * 8;
    const float* src = Vg + (size_t)(b * T_ + t) * M_ + m0 + mc;
    const float4 a = *reinterpret_cast<const float4*>(src);
    const float4 d = *reinterpret_cast<const float4*>(src + 4);
    f16x8 o;
    o[0] = (f16)a.x; o[1] = (f16)a.y; o[2] = (f16)a.z; o[3] = (f16)a.w;
    o[4] = (f16)d.x; o[5] = (f16)d.y; o[6] = (f16)d.z; o[7] = (f16)d.w;
    f16* dst = pv + ((size_t)(b * NT + mt) * T_ + t) * KVB + c * 8;
    *reinterpret_cast<f16x8*>(dst) = o;
  }
}

// -------- main attention: softmax[mt] || PV[mt-1] pipelined, counted vmcnt --------
__global__ __launch_bounds__(512, 2) void fattn(
    const float* __restrict__ Qg, const f16* __restrict__ pk,
    const f16* __restrict__ pv, float* __restrict__ Og)
{
  __shared__ __align__(16) f16 Ks[2][KT_F16];
  __shared__ __align__(16) f16 Vs[2][VT_F16];
  __shared__ __align__(16) f16 Ps[2][NBLK * KVB];
  __shared__ float redmax[2][NBLK];
  __shared__ float redsum[2][NBLK];
  __shared__ float stat_al[2][NBLK];
  __shared__ float stat_il[NBLK];

  const int raw = blockIdx.x;
  const int bid = (raw & 7) * 64 + (raw >> 3);   // XCD <-> batch (L2 locality)
  const int b   = bid >> 6;
  const int nb  = (bid & 63) << 6;
  const int tid  = threadIdx.x;
  const int wv   = tid >> 6;
  const int lane = tid & 63;
  const int l15  = lane & 15;
  const int lq   = lane >> 4;
  const int ms   = wv & 1;
  const int ng   = wv >> 1;

  const char* kbase = (const char*)(pk + (size_t)b * NT * KT_F16);
  const char* vbase = (const char*)(pv + (size_t)b * NT * VT_F16);
  const int lo = wv * 1024;

  // prologue staging: ALL K0 first, then ALL V0 (FIFO order matters for vmcnt(4))
  #pragma unroll
  for (int r = 0; r < 4; ++r)
    gld16(kbase + r * 8192 + lo + lane * 16, (char*)&Ks[0][0] + r * 8192 + lo);
  #pragma unroll
  for (int r = 0; r < 4; ++r)
    gld16(vbase + r * 8192 + lo + lane * 16, (char*)&Vs[0][0] + r * 8192 + lo);

  // Q fragments fp16 hi+lo (split-fp16 QK^T numerics, proven)
  f16x8 qh[16], ql[16];
  {
    const float* qrow = Qg + (size_t)(b * N_ + nb + ng * 16 + l15) * T_;
    #pragma unroll
    for (int ks = 0; ks < 16; ++ks) {
      const int k0 = ks * 32 + lq * 8;
      float f[8];
      *reinterpret_cast<float4*>(&f[0]) = *reinterpret_cast<const float4*>(qrow + k0);
      *reinterpret_cast<float4*>(&f[4]) = *reinterpret_cast<const float4*>(qrow + k0 + 4);
      f16x8 h, l;
      #pragma unroll
      for (int j = 0; j < 8; ++j) { h[j] = (f16)f[j]; l[j] = (f16)(f[j] - (float)h[j]); }
      qh[ks] = h; ql[ks] = l;
    }
  }

  f32x4 oacc[4][4];
  #pragma unroll
  for (int tf = 0; tf < 4; ++tf)
    #pragma unroll
    for (int nf = 0; nf < 4; ++nf)
      oacc[tf][nf] = f32x4{0.f, 0.f, 0.f, 0.f};

  float m_run = -INFINITY;
  float l_run = 0.f;
  float aprev[4] = {1.f, 1.f, 1.f, 1.f};   // alpha[mt-1] per n-group

  for (int mt = 0; mt < NT; ++mt) {
    const int cur = mt & 1;
    const int prv = cur ^ 1;

    // B0: drain K[mt] (+V[mt-1]); V[mt] stays in flight (counted, never 0)
    asm volatile("s_waitcnt vmcnt(4)" ::: "memory");
    __builtin_amdgcn_s_barrier();
    __builtin_amdgcn_sched_barrier(0);

    // issue K[mt+1] (safe: all waves past S[mt-1] via B0)
    if (mt + 1 < NT) {
      const char* kt = kbase + (size_t)(mt + 1) * (KT_F16 * 2);
      char* kd = (char*)&Ks[prv][0];
      #pragma unroll
      for (int r = 0; r < 4; ++r)
        gld16(kt + r * 8192 + lo + lane * 16, kd + r * 8192 + lo);
    }

    // ---- S^T (MFMA) with O-rescale[mt-1] (VALU) in its shadow
    f32x4 sh = f32x4{0.f, 0.f, 0.f, 0.f};
    f32x4 sl = f32x4{0.f, 0.f, 0.f, 0.f};
    {
      const f16* KsC = &Ks[cur][0];
      const int mrow = ms * 16 + l15;
      const int mb2 = mrow * T_;
      const int mx = mrow & 7;
      __builtin_amdgcn_s_setprio(1);
      #pragma unroll
      for (int ks = 0; ks < 16; ++ks) {
        const int c = ((ks << 2) + lq) ^ mx;
        const f16x8 a = *reinterpret_cast<const f16x8*>(KsC + mb2 + c * 8);
        sh = __builtin_amdgcn_mfma_f32_16x16x32_f16(a, qh[ks], sh, 0, 0, 0);
        sl = __builtin_amdgcn_mfma_f32_16x16x32_f16(a, ql[ks], sl, 0, 0, 0);
      }
      __builtin_amdgcn_s_setprio(0);
    }
    // rescale by alpha[mt-1] (T13-gated), scheduled under the MFMA block above
    if (__any((aprev[0] != 1.0f) || (aprev[1] != 1.0f) ||
              (aprev[2] != 1.0f) || (aprev[3] != 1.0f))) {
      #pragma unroll
      for (int nf = 0; nf < 4; ++nf) {
        const float av = aprev[nf];
        #pragma unroll
        for (int tf = 0; tf < 4; ++tf) {
          oacc[tf][nf][0] *= av; oacc[tf][nf][1] *= av;
          oacc[tf][nf][2] *= av; oacc[tf][nf][3] *= av;
        }
      }
    }
    const f32x4 sacc = sh + sl;

    const int n = ng * 16 + l15;
    float tmax = fmaxf(fmaxf(sacc[0], sacc[1]), fmaxf(sacc[2], sacc[3]));
    tmax = fmaxf(tmax, __shfl_xor(tmax, 16));
    tmax = fmaxf(tmax, __shfl_xor(tmax, 32));
    if (lane < 16) redmax[ms][ng * 16 + lane] = tmax;
    asm volatile("s_waitcnt lgkmcnt(0)" ::: "memory");
    __builtin_amdgcn_s_barrier();                        // B1
    __builtin_amdgcn_sched_barrier(0);

    // ---- softmax[mt] (VALU/trans) interleaved with PV[mt-1] (MFMA)
    const float gmax = fmaxf(redmax[0][n], redmax[1][n]);
    const float mnew = fmaxf(m_run, gmax);
    const float alpha = __expf(m_run - mnew);            // first tile: 0
    const float p0 = __expf(sacc[0] - mnew);
    const float p1 = __expf(sacc[1] - mnew);
    const float p2 = __expf(sacc[2] - mnew);
    const float p3 = __expf(sacc[3] - mnew);
    {
      f16x4 pw;
      pw[0] = (f16)p0; pw[1] = (f16)p1; pw[2] = (f16)p2; pw[3] = (f16)p3;
      const int ch = (ms * 2 + (lq >> 1)) ^ ((n >> 1) & 3);
      *reinterpret_cast<f16x4*>(&Ps[cur][n * KVB + ch * 8 + (lq & 1) * 4]) = pw;
    }
    if (ms == 0 && lane < 16) stat_al[cur][ng * 16 + lane] = alpha;
    float psum = (p0 + p1) + (p2 + p3);
    psum += __shfl_xor(psum, 16);
    psum += __shfl_xor(psum, 32);
    if (lane < 16) redsum[ms][ng * 16 + lane] = psum;

    if (mt > 0) {      // PV for tile mt-1: inputs (Ps[prv], Vs[prv]) all ready pre-B1
      f16x8 vfr[4];
      #pragma unroll
      for (int tf = 0; tf < 4; ++tf) {
        const int t = wv * 64 + tf * 16 + l15;
        vfr[tf] = *reinterpret_cast<const f16x8*>(
            &Vs[prv][t * KVB + (lq ^ ((t >> 1) & 3)) * 8]);
      }
      __builtin_amdgcn_s_setprio(1);
      #pragma unroll
      for (int nf = 0; nf < 4; ++nf) {
        const int n2 = nf * 16 + l15;
        const f16x8 pfr = *reinterpret_cast<const f16x8*>(
            &Ps[prv][n2 * KVB + (lq ^ ((n2 >> 1) & 3)) * 8]);
        #pragma unroll
        for (int tf = 0; tf < 4; ++tf)
          oacc[tf][nf] = __builtin_amdgcn_mfma_f32_16x16x32_f16(vfr[tf], pfr, oacc[tf][nf], 0, 0, 0);
      }
      __builtin_amdgcn_s_setprio(0);
    }
    asm volatile("s_waitcnt lgkmcnt(0)" ::: "memory");
    __builtin_amdgcn_s_barrier();                        // B2
    __builtin_amdgcn_sched_barrier(0);

    l_run = l_run * alpha + redsum[0][n] + redsum[1][n];
    m_run = mnew;
    // alphas for next iteration's rescale (reads of stat_al[cur] post-B2)
    aprev[0] = stat_al[cur][l15];
    aprev[1] = stat_al[cur][16 + l15];
    aprev[2] = stat_al[cur][32 + l15];
    aprev[3] = stat_al[cur][48 + l15];

    // issue V[mt+1] (safe: PV[mt-1] reads of Vs[prv] fenced by B2)
    if (mt + 1 < NT) {
      const char* vt = vbase + (size_t)(mt + 1) * (VT_F16 * 2);
      char* vd = (char*)&Vs[prv][0];
      #pragma unroll
      for (int r = 0; r < 4; ++r)
        gld16(vt + r * 8192 + lo + lane * 16, vd + r * 8192 + lo);
    }
  }

  // ---- drain tail: PV[NT-1]
  __syncthreads();   // vmcnt(0)+lgkmcnt(0)+barrier: V[NT-1] resident
  {
    const int pi = (NT - 1) & 1;
    if (__any((aprev[0] != 1.0f) || (aprev[1] != 1.0f) ||
              (aprev[2] != 1.0f) || (aprev[3] != 1.0f))) {
      #pragma unroll
      for (int nf = 0; nf < 4; ++nf) {
        const float av = aprev[nf];
        #pragma unroll
        for (int tf = 0; tf < 4; ++tf) {
          oacc[tf][nf][0] *= av; oacc[tf][nf][1] *= av;
          oacc[tf][nf][2] *= av; oacc[tf][nf][3] *= av;
        }
      }
    }
    f16x8 vfr[4];
    #pragma unroll
    for (int tf = 0; tf < 4; ++tf) {
      const int t = wv * 64 + tf * 16 + l15;
      vfr[tf] = *reinterpret_cast<const f16x8*>(
          &Vs[pi][t * KVB + (lq ^ ((t >> 1) & 3)) * 8]);
    }
    #pragma unroll
    for (int nf = 0; nf < 4; ++nf) {
      const int n2 = nf * 16 + l15;
      const f16x8 pfr = *reinterpret_cast<const f16x8*>(
          &Ps[pi][n2 * KVB + (lq ^ ((n2 >> 1) & 3)) * 8]);
      #pragma unroll
      for (int tf = 0; tf < 4; ++tf)
        oacc[tf][nf] = __builtin_amdgcn_mfma_f32_16x16x32_f16(vfr[tf], pfr, oacc[tf][nf], 0, 0, 0);
    }
  }

  // ---- epilogue: O[b][n][t] = O^T[t][n] / l[n]
  if (ms == 0 && lane < 16) stat_il[ng * 16 + lane] = 1.0f / l_run;
  __syncthreads();
  #pragma unroll
  for (int nf = 0; nf < 4; ++nf) {
    const float il = stat_il[nf * 16 + l15];
    const size_t base = (size_t)(b * N_ + nb + nf * 16 + l15) * T_;
    #pragma unroll
    for (int tf = 0; tf < 4; ++tf) {
      const int t = wv * 64 + tf * 16 + lq * 4;
      float4 o;
      o.x = oacc[tf][nf][0] * il;
      o.y = oacc[tf][nf][1] * il;
      o.z = oacc[tf][nf][2] * il;
      o.w = oacc[tf][nf][3] * il;
      *reinterpret_cast<float4*>(Og + base + t) = o;
    }
  }
}

// ---------------- fallback (R2-proven, no ws): 8-wave 64-n block ----------------
#define KSTR 520
#define PSTRF 48
__global__ __launch_bounds__(512, 2) void fattn_fb(
    const float* __restrict__ Qg, const float* __restrict__ Kg,
    const float* __restrict__ Vg, float* __restrict__ Og)
{
  __shared__ __align__(16) f16 Ksf[KVB * KSTR];
  __shared__ __align__(16) f16 Vsf[T_ * KVB];
  __shared__ __align__(16) f16 Psf[64 * PSTRF];
  __shared__ float redmax[2][64];
  __shared__ float redsum[2][64];
  __shared__ float stat_al[64];
  __shared__ float stat_il[64];

  const int bid  = blockIdx.x;
  const int b    = bid >> 6;
  const int nb   = (bid & 63) << 6;
  const int tid  = threadIdx.x;
  const int w    = tid >> 6;
  const int lane = tid & 63;
  const int l15  = lane & 15;
  const int lq   = lane >> 4;
  const int ms   = w & 1;
  const int ng   = w >> 1;

  f16x8 qh[16], ql[16];
  {
    const float* qrow = Qg + (size_t)(b * N_ + nb + ng * 16 + l15) * T_;
    #pragma unroll
    for (int ks = 0; ks < 16; ++ks) {
      const int k0 = ks * 32 + lq * 8;
      float f[8];
      *reinterpret_cast<float4*>(&f[0]) = *reinterpret_cast<const float4*>(qrow + k0);
      *reinterpret_cast<float4*>(&f[4]) = *reinterpret_cast<const float4*>(qrow + k0 + 4);
      f16x8 h, l;
      #pragma unroll
      for (int j = 0; j < 8; ++j) { h[j] = (f16)f[j]; l[j] = (f16)(f[j] - (float)h[j]); }
      qh[ks] = h; ql[ks] = l;
    }
  }
  f32x4 oacc[4][4];
  #pragma unroll
  for (int tf = 0; tf < 4; ++tf)
    #pragma unroll
    for (int nf = 0; nf < 4; ++nf)
      oacc[tf][nf] = f32x4{0.f, 0.f, 0.f, 0.f};
  float m_run = -INFINITY, l_run = 0.f;

  for (int mt = 0; mt < M_ / KVB; ++mt) {
    const int m0 = mt * KVB;
    #pragma unroll
    for (int r = 0; r < 8; ++r) {
      const int task = r * 512 + tid;
      const int m  = task & 31;
      const int t0 = (task >> 5) << 2;
      const float* src = Kg + (size_t)(b * T_ + t0) * M_ + m0 + m;
      f16x4 kk;
      kk[0] = (f16)src[0]; kk[1] = (f16)src[M_];
      kk[2] = (f16)src[2 * M_]; kk[3] = (f16)src[3 * M_];
      *reinterpret_cast<f16x4*>(&Ksf[m * KSTR + t0]) = kk;
    }
    #pragma unroll
    for (int r = 0; r < 4; ++r) {
      const int idx = r * 512 + tid;
      const int t  = idx >> 2;
      const int mc = (idx & 3) << 3;
      const float* src = Vg + (size_t)(b * T_ + t) * M_ + m0 + mc;
      const float4 f0 = *reinterpret_cast<const float4*>(src);
      const float4 f1 = *reinterpret_cast<const float4*>(src + 4);
      f16x8 v8;
      v8[0] = (f16)f0.x; v8[1] = (f16)f0.y; v8[2] = (f16)f0.z; v8[3] = (f16)f0.w;
      v8[4] = (f16)f1.x; v8[5] = (f16)f1.y; v8[6] = (f16)f1.z; v8[7] = (f16)f1.w;
      *reinterpret_cast<f16x8*>(&Vsf[t * KVB + (mc ^ ((t & 3) << 3))]) = v8;
    }
    __syncthreads();
    f32x4 sacc = f32x4{0.f, 0.f, 0.f, 0.f};
    {
      const int abase = (ms * 16 + l15) * KSTR + lq * 8;
      #pragma unroll
      for (int ks = 0; ks < 16; ++ks) {
        const f16x8 a = *reinterpret_cast<const f16x8*>(&Ksf[abase + ks * 32]);
        sacc = __builtin_amdgcn_mfma_f32_16x16x32_f16(a, qh[ks], sacc, 0, 0, 0);
        sacc = __builtin_amdgcn_mfma_f32_16x16x32_f16(a, ql[ks], sacc, 0, 0, 0);
      }
    }
    const int n = ng * 16 + l15;
    float tmax = fmaxf(fmaxf(sacc[0], sacc[1]), fmaxf(sacc[2], sacc[3]));
    tmax = fmaxf(tmax, __shfl_xor(tmax, 16));
    tmax = fmaxf(tmax, __shfl_xor(tmax, 32));
    if (lane < 16) redmax[ms][ng * 16 + lane] = tmax;
    __syncthreads();
    const float gmax = fmaxf(redmax[0][n], redmax[1][n]);
    const float mnew = fmaxf(m_run, gmax);
    const float alpha = __expf(m_run - mnew);
    if (ms == 0 && lane < 16) stat_al[ng * 16 + lane] = alpha;
    const float p0 = __expf(sacc[0] - mnew);
    const float p1 = __expf(sacc[1] - mnew);
    const float p2 = __expf(sacc[2] - mnew);
    const float p3 = __expf(sacc[3] - mnew);
    float psum = (p0 + p1) + (p2 + p3);
    psum += __shfl_xor(psum, 16);
    psum += __shfl_xor(psum, 32);
    if (lane < 16) redsum[ms][ng * 16 + lane] = psum;
    {
      f16x4 pw;
      pw[0] = (f16)p0; pw[1] = (f16)p1; pw[2] = (f16)p2; pw[3] = (f16)p3;
      *reinterpret_cast<f16x4*>(&Psf[n * PSTRF + ms * 16 + lq * 4]) = pw;
    }
    __syncthreads();
    l_run = l_run * alpha + redsum[0][n] + redsum[1][n];
    m_run = mnew;
    #pragma unroll
    for (int nf = 0; nf < 4; ++nf) {
      const float av = stat_al[nf * 16 + l15];
      #pragma unroll
      for (int tf = 0; tf < 4; ++tf) {
        oacc[tf][nf][0] *= av; oacc[tf][nf][1] *= av;
        oacc[tf][nf][2] *= av; oacc[tf][nf][3] *= av;
      }
    }
    {
      f16x8 vfr[4];
      #pragma unroll
      for (int tf = 0; tf < 4; ++tf) {
        const int t = w * 64 + tf * 16 + l15;
        vfr[tf] = *reinterpret_cast<const f16x8*>(&Vsf[t * KVB + ((lq * 8) ^ ((t & 3) << 3))]);
      }
      #pragma unroll
      for (int nf = 0; nf < 4; ++nf) {
        const f16x8 pfr = *reinterpret_cast<const f16x8*>(&Psf[(nf * 16 + l15) * PSTRF + lq * 8]);
        #pragma unroll
        for (int tf = 0; tf < 4; ++tf)
          oacc[tf][nf] = __builtin_amdgcn_mfma_f32_16x16x32_f16(vfr[tf], pfr, oacc[tf][nf], 0, 0, 0);
      }
    }
    __syncthreads();
  }
  if (ms == 0 && lane < 16) stat_il[ng * 16 + lane] = 1.0f / l_run;
  __syncthreads();
  #pragma unroll
  for (int nf = 0; nf < 4; ++nf) {
    const float il = stat_il[nf * 16 + l15];
    const size_t base = (size_t)(b * N_ + nb + nf * 16 + l15) * T_;
    #pragma unroll
    for (int tf = 0; tf < 4; ++tf) {
      const int t = w * 64 + tf * 16 + lq * 4;
      float4 o;
      o.x = oacc[tf][nf][0] * il;
      o.y = oacc[tf][nf][1] * il;
      o.z = oacc[tf][nf][2] * il;
      o.w = oacc[tf][nf][3] * il;
      *reinterpret_cast<float4*>(Og + base + t) = o;
    }
  }
}

extern "C" void kernel_launch(void* const* d_in, const int* in_sizes, int n_in,
                              void* d_out, int out_size, void* d_ws, size_t ws_size,
                              hipStream_t stream) {
  const float* Q = (const float*)d_in[0];
  const float* K = (const float*)d_in[1];
  const float* V = (const float*)d_in[2];
  float* O = (float*)d_out;
  (void)in_sizes; (void)n_in; (void)out_size;

  const size_t needed = (size_t)B_ * NT * KT_F16 * 2 * 2;  // pk + pv = 64MB
  if (ws_size >= needed) {
    f16* pk = (f16*)d_ws;
    f16* pv = pk + (size_t)B_ * NT * KT_F16;
    pack_k<<<dim3(B_ * NT * 8), dim3(256), 0, stream>>>(K, pk);
    pack_v<<<dim3(B_ * NT), dim3(256), 0, stream>>>(V, pv);
    fattn<<<dim3(B_ * (N_ / NBLK)), dim3(512), 0, stream>>>(Q, pk, pv, O);
  } else {
    fattn_fb<<<dim3(B_ * (N_ / NBLK)), dim3(512), 0, stream>>>(Q, K, V, O);
  }
}

// Round 8
// 456.385 us; speedup vs baseline: 1.3644x; 1.3644x over previous
//
#include <hip/hip_runtime.h>
#include <hip/hip_bf16.h>
#include <stdint.h>

#define B_ 8
#define N_ 4096
#define T_ 512
#define M_ 4096
#define KVB 32
#define NBLK 64
#define NT 128            // 32-m tiles in packed images
#define NDT 64            // double-tiles processed by main loop
#define KT_F16 (KVB*T_)   // 16384 f16 = 32KB per packed K tile
#define VT_F16 (T_*KVB)   // 16384 f16 = 32KB per packed V tile

typedef _Float16 f16;
typedef __attribute__((ext_vector_type(8))) f16 f16x8;
typedef __attribute__((ext_vector_type(4))) f16 f16x4;
typedef __attribute__((ext_vector_type(4))) float f32x4;

__device__ __forceinline__ void gld16(const void* g, void* l) {
  __builtin_amdgcn_global_load_lds(
      (const __attribute__((address_space(1))) unsigned int*)g,
      (__attribute__((address_space(3))) unsigned int*)l, 16, 0, 0);
}

// ---------------- pack kernels ----------------
// K image (proven R3-R7): per 32-m tile [m 0..31][chunk s 0..63] (16B):
//   chunk s holds fp16 K[b][t=(s^(m&7))*8 .. +8][m0+m]
__global__ __launch_bounds__(256) void pack_k(const float* __restrict__ Kg,
                                              f16* __restrict__ pk) {
  const int bx = blockIdx.x;
  const int ts = bx & 7;            // 64-t slab
  const int mt = (bx >> 3) & (NT - 1);
  const int b  = bx >> 10;
  const int m0 = mt * KVB;
  const int tid = threadIdx.x;
  __shared__ float tileT[64][33];
  {
    const int tl = tid >> 2;
    const int mseg = (tid & 3) * 8;
    const float* src = Kg + (size_t)(b * T_ + ts * 64 + tl) * M_ + m0 + mseg;
    const float4 a = *reinterpret_cast<const float4*>(src);
    const float4 c = *reinterpret_cast<const float4*>(src + 4);
    tileT[tl][mseg + 0] = a.x; tileT[tl][mseg + 1] = a.y;
    tileT[tl][mseg + 2] = a.z; tileT[tl][mseg + 3] = a.w;
    tileT[tl][mseg + 4] = c.x; tileT[tl][mseg + 5] = c.y;
    tileT[tl][mseg + 6] = c.z; tileT[tl][mseg + 7] = c.w;
  }
  __syncthreads();
  {
    const int m  = tid >> 3;
    const int jl = tid & 7;
    const int tlc = (jl ^ (m & 7)) * 8;
    f16x8 o;
    #pragma unroll
    for (int i = 0; i < 8; ++i) o[i] = (f16)tileT[tlc + i][m];
    f16* dst = pk + ((size_t)(b * NT + mt) * KVB + m) * T_ + (ts * 8 + jl) * 8;
    *reinterpret_cast<f16x8*>(dst) = o;
  }
}

// V image (proven R4/R5): exact PV A-fragment order. Per 32-m tile:
//   [tslot 0..31][lane 0..63]: lane holds fp16 V[b][tslot*16+(lane&15)][m0+(lane>>4)*8 ..+8]
__global__ __launch_bounds__(256) void pack_v(const float* __restrict__ Vg,
                                              f16* __restrict__ pv) {
  const int bx = blockIdx.x;        // b*NT + mt
  const int mt = bx & (NT - 1);
  const int b  = bx >> 7;
  const int m0 = mt * KVB;
  const int tid = threadIdx.x;
  #pragma unroll
  for (int it = 0; it < 8; ++it) {
    const int task = it * 256 + tid;      // 0..2047
    const int ts = task >> 6;
    const int ln = task & 63;
    const int t  = ts * 16 + (ln & 15);
    const int mc = (ln >> 4) * 8;
    const float* src = Vg + (size_t)(b * T_ + t) * M_ + m0 + mc;
    const float4 a = *reinterpret_cast<const float4*>(src);
    const float4 d = *reinterpret_cast<const float4*>(src + 4);
    f16x8 o;
    o[0] = (f16)a.x; o[1] = (f16)a.y; o[2] = (f16)a.z; o[3] = (f16)a.w;
    o[4] = (f16)d.x; o[5] = (f16)d.y; o[6] = (f16)d.z; o[7] = (f16)d.w;
    *reinterpret_cast<f16x8*>(pv + ((size_t)bx * 2048 + task) * 8) = o;
  }
}

// ------- main attention: 64-m double-tiles, pure-fp16 Q, V in registers -------
__global__ __launch_bounds__(512, 2) void fattn(
    const float* __restrict__ Qg, const f16* __restrict__ pk,
    const f16* __restrict__ pv, float* __restrict__ Og)
{
  __shared__ __align__(16) f16 Ks[2][64 * T_];    // 128KB dbuf: [sub*32 + m][t]
  __shared__ __align__(16) f16 Ps[NBLK * 64];     // 8KB: [n][m0..63], 128B rows, chunk-XOR
  __shared__ float redmax[2][NBLK];
  __shared__ float redsum[2][NBLK];
  __shared__ float stat_al[NBLK];
  __shared__ float stat_il[NBLK];

  const int raw = blockIdx.x;
  const int bid = (raw & 7) * 64 + (raw >> 3);   // XCD <-> batch (L2 locality)
  const int b   = bid >> 6;
  const int nb  = (bid & 63) << 6;
  const int tid  = threadIdx.x;
  const int wv   = tid >> 6;
  const int lane = tid & 63;
  const int l15  = lane & 15;
  const int lq   = lane >> 4;
  const int ms   = wv & 1;                       // 16-m half within each 32-sub
  const int ng   = wv >> 1;                      // 16-n group (softmax owner)

  const char* kbase = (const char*)(pk + (size_t)b * NT * KT_F16);
  const f16*  pvb   = pv + (size_t)b * NT * VT_F16;
  const int lo = wv * 8192;                      // per-wave 8KB slice of 64KB K dbl-tile

  // prologue: stage K double-tile 0 (8 gld16/lane, contiguous slices)
  #pragma unroll
  for (int r = 0; r < 8; ++r)
    gld16(kbase + lo + r * 1024 + lane * 16, (char*)&Ks[0][0] + lo + r * 1024 + lane * 16);

  // V fragments for double-tile 0 -> regs (wave's 64-t slice x both 32-m subs)
  f16x8 vfr[8];
  #pragma unroll
  for (int s = 0; s < 2; ++s)
    #pragma unroll
    for (int tf = 0; tf < 4; ++tf)
      vfr[s * 4 + tf] = *reinterpret_cast<const f16x8*>(
          pvb + ((size_t)s * 2048 + (wv * 4 + tf) * 64 + lane) * 8);

  // Q fragments: fp16 hi only (validated numerics model: absmax ~0.044 < 0.1025)
  f16x8 qh[16];
  {
    const float* qrow = Qg + (size_t)(b * N_ + nb + ng * 16 + l15) * T_;
    #pragma unroll
    for (int ks = 0; ks < 16; ++ks) {
      const int k0 = ks * 32 + lq * 8;
      float f[8];
      *reinterpret_cast<float4*>(&f[0]) = *reinterpret_cast<const float4*>(qrow + k0);
      *reinterpret_cast<float4*>(&f[4]) = *reinterpret_cast<const float4*>(qrow + k0 + 4);
      f16x8 h;
      #pragma unroll
      for (int j = 0; j < 8; ++j) h[j] = (f16)f[j];
      qh[ks] = h;
    }
  }

  // O^T acc: wave owns t in [wv*64, +64), all 64 n. [tf 0..3][nf 0..3]
  f32x4 oacc[4][4];
  #pragma unroll
  for (int tf = 0; tf < 4; ++tf)
    #pragma unroll
    for (int nf = 0; nf < 4; ++nf)
      oacc[tf][nf] = f32x4{0.f, 0.f, 0.f, 0.f};

  float m_run = -INFINITY;
  float l_run = 0.f;

  __syncthreads();   // full drain: K0 resident, vfr/Q in regs

  const int n = ng * 16 + l15;
  const int n7 = n & 7;

  for (int dt = 0; dt < NDT; ++dt) {
    const int cur = dt & 1;

    // issue K[dt+1] (8 gld16; stays in flight across B1/B2, drained at B3)
    if (dt + 1 < NDT) {
      const char* kt = kbase + (size_t)(dt + 1) * 65536;
      char* kd = (char*)&Ks[cur ^ 1][0];
      #pragma unroll
      for (int r = 0; r < 8; ++r)
        gld16(kt + lo + r * 1024 + lane * 16, kd + lo + r * 1024 + lane * 16);
    }

    // ---- S^T over 64 m: two independent chains (sub 0/1 share qh)
    f32x4 s0 = f32x4{0.f, 0.f, 0.f, 0.f};
    f32x4 s1 = f32x4{0.f, 0.f, 0.f, 0.f};
    {
      const f16* KsC = &Ks[cur][0];
      const int mrow = ms * 16 + l15;        // local within each 32-sub
      const int base0 = mrow * T_;           // sub 0 row
      const int mx = mrow & 7;               // same for both subs
      __builtin_amdgcn_s_setprio(1);
      #pragma unroll
      for (int ks = 0; ks < 16; ++ks) {
        const int c = ((ks << 2) + lq) ^ mx;
        const f16x8 a0 = *reinterpret_cast<const f16x8*>(KsC + base0 + c * 8);
        const f16x8 a1 = *reinterpret_cast<const f16x8*>(KsC + base0 + 32 * T_ + c * 8);
        s0 = __builtin_amdgcn_mfma_f32_16x16x32_f16(a0, qh[ks], s0, 0, 0, 0);
        s1 = __builtin_amdgcn_mfma_f32_16x16x32_f16(a1, qh[ks], s1, 0, 0, 0);
      }
      __builtin_amdgcn_s_setprio(0);
    }

    // ---- one softmax round per 64 m (cross-ms combine through LDS)
    float tmax = fmaxf(fmaxf(fmaxf(s0[0], s0[1]), fmaxf(s0[2], s0[3])),
                       fmaxf(fmaxf(s1[0], s1[1]), fmaxf(s1[2], s1[3])));
    tmax = fmaxf(tmax, __shfl_xor(tmax, 16));
    tmax = fmaxf(tmax, __shfl_xor(tmax, 32));
    if (lane < 16) redmax[ms][ng * 16 + lane] = tmax;
    asm volatile("s_waitcnt lgkmcnt(0)" ::: "memory");
    __builtin_amdgcn_s_barrier();                        // B1 (vmcnt stays live)
    __builtin_amdgcn_sched_barrier(0);

    const float gmax = fmaxf(redmax[0][n], redmax[1][n]);
    const float mnew = fmaxf(m_run, gmax);
    const float alpha = __expf(m_run - mnew);            // first tile: 0
    if (ms == 0 && lane < 16) stat_al[ng * 16 + lane] = alpha;
    const float p0 = __expf(s0[0] - mnew);
    const float p1 = __expf(s0[1] - mnew);
    const float p2 = __expf(s0[2] - mnew);
    const float p3 = __expf(s0[3] - mnew);
    const float p4 = __expf(s1[0] - mnew);
    const float p5 = __expf(s1[1] - mnew);
    const float p6 = __expf(s1[2] - mnew);
    const float p7 = __expf(s1[3] - mnew);
    float psum = ((p0 + p1) + (p2 + p3)) + ((p4 + p5) + (p6 + p7));
    psum += __shfl_xor(psum, 16);
    psum += __shfl_xor(psum, 32);
    if (lane < 16) redsum[ms][ng * 16 + lane] = psum;
    {
      // Ps rows: 64 m = 8 chunks of 16B; chunk-XOR by (n&7) for conflict-free b128 reads
      f16x4 w0, w1;
      w0[0] = (f16)p0; w0[1] = (f16)p1; w0[2] = (f16)p2; w0[3] = (f16)p3;
      w1[0] = (f16)p4; w1[1] = (f16)p5; w1[2] = (f16)p6; w1[3] = (f16)p7;
      const int chb = ms * 2 + (lq >> 1);
      const int e = (lq & 1) * 4;
      *reinterpret_cast<f16x4*>(&Ps[n * 64 + ((chb) ^ n7) * 8 + e]) = w0;
      *reinterpret_cast<f16x4*>(&Ps[n * 64 + ((chb + 4) ^ n7) * 8 + e]) = w1;
    }
    asm volatile("s_waitcnt lgkmcnt(0)" ::: "memory");
    __builtin_amdgcn_s_barrier();                        // B2
    __builtin_amdgcn_sched_barrier(0);

    l_run = l_run * alpha + redsum[0][n] + redsum[1][n];
    m_run = mnew;

    // ---- PV: conditional rescale (T13), then O^T += V * P^T over 64 m
    {
      const float al0 = stat_al[l15];
      const float al1 = stat_al[16 + l15];
      const float al2 = stat_al[32 + l15];
      const float al3 = stat_al[48 + l15];
      if (__any((al0 != 1.0f) || (al1 != 1.0f) || (al2 != 1.0f) || (al3 != 1.0f))) {
        #pragma unroll
        for (int nf = 0; nf < 4; ++nf) {
          const float av = nf == 0 ? al0 : (nf == 1 ? al1 : (nf == 2 ? al2 : al3));
          #pragma unroll
          for (int tf = 0; tf < 4; ++tf) {
            oacc[tf][nf][0] *= av; oacc[tf][nf][1] *= av;
            oacc[tf][nf][2] *= av; oacc[tf][nf][3] *= av;
          }
        }
      }
    }
    __builtin_amdgcn_s_setprio(1);
    #pragma unroll
    for (int s = 0; s < 2; ++s) {
      #pragma unroll
      for (int nf = 0; nf < 4; ++nf) {
        const int n2 = nf * 16 + l15;
        const f16x8 pfr = *reinterpret_cast<const f16x8*>(
            &Ps[n2 * 64 + (((s * 4 + lq)) ^ (n2 & 7)) * 8]);
        #pragma unroll
        for (int tf = 0; tf < 4; ++tf)
          oacc[tf][nf] = __builtin_amdgcn_mfma_f32_16x16x32_f16(vfr[s * 4 + tf], pfr, oacc[tf][nf], 0, 0, 0);
      }
    }
    __builtin_amdgcn_s_setprio(0);

    // issue V[dt+1] register loads (consumed next iter; in flight past B3)
    if (dt + 1 < NDT) {
      #pragma unroll
      for (int s = 0; s < 2; ++s)
        #pragma unroll
        for (int tf = 0; tf < 4; ++tf)
          vfr[s * 4 + tf] = *reinterpret_cast<const f16x8*>(
              pvb + ((size_t)(2 * (dt + 1) + s) * 2048 + (wv * 4 + tf) * 64 + lane) * 8);
    }

    // B3: drain the 8 K[dt+1] LDS writes; leave the 8 V loads in flight
    asm volatile("s_waitcnt vmcnt(8)" ::: "memory");
    __builtin_amdgcn_s_barrier();
    __builtin_amdgcn_sched_barrier(0);
  }

  // ---- epilogue: O[b][n][t] = O^T[t][n] / l[n]
  if (ms == 0 && lane < 16) stat_il[ng * 16 + lane] = 1.0f / l_run;
  __syncthreads();
  #pragma unroll
  for (int nf = 0; nf < 4; ++nf) {
    const float il = stat_il[nf * 16 + l15];
    const size_t base = (size_t)(b * N_ + nb + nf * 16 + l15) * T_;
    #pragma unroll
    for (int tf = 0; tf < 4; ++tf) {
      const int t = wv * 64 + tf * 16 + lq * 4;
      float4 o;
      o.x = oacc[tf][nf][0] * il;
      o.y = oacc[tf][nf][1] * il;
      o.z = oacc[tf][nf][2] * il;
      o.w = oacc[tf][nf][3] * il;
      *reinterpret_cast<float4*>(Og + base + t) = o;
    }
  }
}

// ---------------- fallback (R2-proven, no ws): 8-wave 64-n block ----------------
#define KSTR 520
#define PSTRF 48
__global__ __launch_bounds__(512, 2) void fattn_fb(
    const float* __restrict__ Qg, const float* __restrict__ Kg,
    const float* __restrict__ Vg, float* __restrict__ Og)
{
  __shared__ __align__(16) f16 Ksf[KVB * KSTR];
  __shared__ __align__(16) f16 Vsf[T_ * KVB];
  __shared__ __align__(16) f16 Psf[64 * PSTRF];
  __shared__ float redmax[2][64];
  __shared__ float redsum[2][64];
  __shared__ float stat_al[64];
  __shared__ float stat_il[64];

  const int bid  = blockIdx.x;
  const int b    = bid >> 6;
  const int nb   = (bid & 63) << 6;
  const int tid  = threadIdx.x;
  const int w    = tid >> 6;
  const int lane = tid & 63;
  const int l15  = lane & 15;
  const int lq   = lane >> 4;
  const int ms   = w & 1;
  const int ng   = w >> 1;

  f16x8 qh[16], ql[16];
  {
    const float* qrow = Qg + (size_t)(b * N_ + nb + ng * 16 + l15) * T_;
    #pragma unroll
    for (int ks = 0; ks < 16; ++ks) {
      const int k0 = ks * 32 + lq * 8;
      float f[8];
      *reinterpret_cast<float4*>(&f[0]) = *reinterpret_cast<const float4*>(qrow + k0);
      *reinterpret_cast<float4*>(&f[4]) = *reinterpret_cast<const float4*>(qrow + k0 + 4);
      f16x8 h, l;
      #pragma unroll
      for (int j = 0; j < 8; ++j) { h[j] = (f16)f[j]; l[j] = (f16)(f[j] - (float)h[j]); }
      qh[ks] = h; ql[ks] = l;
    }
  }
  f32x4 oacc[4][4];
  #pragma unroll
  for (int tf = 0; tf < 4; ++tf)
    #pragma unroll
    for (int nf = 0; nf < 4; ++nf)
      oacc[tf][nf] = f32x4{0.f, 0.f, 0.f, 0.f};
  float m_run = -INFINITY, l_run = 0.f;

  for (int mt = 0; mt < M_ / KVB; ++mt) {
    const int m0 = mt * KVB;
    #pragma unroll
    for (int r = 0; r < 8; ++r) {
      const int task = r * 512 + tid;
      const int m  = task & 31;
      const int t0 = (task >> 5) << 2;
      const float* src = Kg + (size_t)(b * T_ + t0) * M_ + m0 + m;
      f16x4 kk;
      kk[0] = (f16)src[0]; kk[1] = (f16)src[M_];
      kk[2] = (f16)src[2 * M_]; kk[3] = (f16)src[3 * M_];
      *reinterpret_cast<f16x4*>(&Ksf[m * KSTR + t0]) = kk;
    }
    #pragma unroll
    for (int r = 0; r < 4; ++r) {
      const int idx = r * 512 + tid;
      const int t  = idx >> 2;
      const int mc = (idx & 3) << 3;
      const float* src = Vg + (size_t)(b * T_ + t) * M_ + m0 + mc;
      const float4 f0 = *reinterpret_cast<const float4*>(src);
      const float4 f1 = *reinterpret_cast<const float4*>(src + 4);
      f16x8 v8;
      v8[0] = (f16)f0.x; v8[1] = (f16)f0.y; v8[2] = (f16)f0.z; v8[3] = (f16)f0.w;
      v8[4] = (f16)f1.x; v8[5] = (f16)f1.y; v8[6] = (f16)f1.z; v8[7] = (f16)f1.w;
      *reinterpret_cast<f16x8*>(&Vsf[t * KVB + (mc ^ ((t & 3) << 3))]) = v8;
    }
    __syncthreads();
    f32x4 sacc = f32x4{0.f, 0.f, 0.f, 0.f};
    {
      const int abase = (ms * 16 + l15) * KSTR + lq * 8;
      #pragma unroll
      for (int ks = 0; ks < 16; ++ks) {
        const f16x8 a = *reinterpret_cast<const f16x8*>(&Ksf[abase + ks * 32]);
        sacc = __builtin_amdgcn_mfma_f32_16x16x32_f16(a, qh[ks], sacc, 0, 0, 0);
        sacc = __builtin_amdgcn_mfma_f32_16x16x32_f16(a, ql[ks], sacc, 0, 0, 0);
      }
    }
    const int n = ng * 16 + l15;
    float tmax = fmaxf(fmaxf(sacc[0], sacc[1]), fmaxf(sacc[2], sacc[3]));
    tmax = fmaxf(tmax, __shfl_xor(tmax, 16));
    tmax = fmaxf(tmax, __shfl_xor(tmax, 32));
    if (lane < 16) redmax[ms][ng * 16 + lane] = tmax;
    __syncthreads();
    const float gmax = fmaxf(redmax[0][n], redmax[1][n]);
    const float mnew = fmaxf(m_run, gmax);
    const float alpha = __expf(m_run - mnew);
    if (ms == 0 && lane < 16) stat_al[ng * 16 + lane] = alpha;
    const float p0 = __expf(sacc[0] - mnew);
    const float p1 = __expf(sacc[1] - mnew);
    const float p2 = __expf(sacc[2] - mnew);
    const float p3 = __expf(sacc[3] - mnew);
    float psum = (p0 + p1) + (p2 + p3);
    psum += __shfl_xor(psum, 16);
    psum += __shfl_xor(psum, 32);
    if (lane < 16) redsum[ms][ng * 16 + lane] = psum;
    {
      f16x4 pw;
      pw[0] = (f16)p0; pw[1] = (f16)p1; pw[2] = (f16)p2; pw[3] = (f16)p3;
      *reinterpret_cast<f16x4*>(&Psf[n * PSTRF + ms * 16 + lq * 4]) = pw;
    }
    __syncthreads();
    l_run = l_run * alpha + redsum[0][n] + redsum[1][n];
    m_run = mnew;
    #pragma unroll
    for (int nf = 0; nf < 4; ++nf) {
      const float av = stat_al[nf * 16 + l15];
      #pragma unroll
      for (int tf = 0; tf < 4; ++tf) {
        oacc[tf][nf][0] *= av; oacc[tf][nf][1] *= av;
        oacc[tf][nf][2] *= av; oacc[tf][nf][3] *= av;
      }
    }
    {
      f16x8 vfr[4];
      #pragma unroll
      for (int tf = 0; tf < 4; ++tf) {
        const int t = w * 64 + tf * 16 + l15;
        vfr[tf] = *reinterpret_cast<const f16x8*>(&Vsf[t * KVB + ((lq * 8) ^ ((t & 3) << 3))]);
      }
      #pragma unroll
      for (int nf = 0; nf < 4; ++nf) {
        const f16x8 pfr = *reinterpret_cast<const f16x8*>(&Psf[(nf * 16 + l15) * PSTRF + lq * 8]);
        #pragma unroll
        for (int tf = 0; tf < 4; ++tf)
          oacc[tf][nf] = __builtin_amdgcn_mfma_f32_16x16x32_f16(vfr[tf], pfr, oacc[tf][nf], 0, 0, 0);
      }
    }
    __syncthreads();
  }
  if (ms == 0 && lane < 16) stat_il[ng * 16 + lane] = 1.0f / l_run;
  __syncthreads();
  #pragma unroll
  for (int nf = 0; nf < 4; ++nf) {
    const float il = stat_il[nf * 16 + l15];
    const size_t base = (size_t)(b * N_ + nb + nf * 16 + l15) * T_;
    #pragma unroll
    for (int tf = 0; tf < 4; ++tf) {
      const int t = w * 64 + tf * 16 + lq * 4;
      float4 o;
      o.x = oacc[tf][nf][0] * il;
      o.y = oacc[tf][nf][1] * il;
      o.z = oacc[tf][nf][2] * il;
      o.w = oacc[tf][nf][3] * il;
      *reinterpret_cast<float4*>(Og + base + t) = o;
    }
  }
}

extern "C" void kernel_launch(void* const* d_in, const int* in_sizes, int n_in,
                              void* d_out, int out_size, void* d_ws, size_t ws_size,
                              hipStream_t stream) {
  const float* Q = (const float*)d_in[0];
  const float* K = (const float*)d_in[1];
  const float* V = (const float*)d_in[2];
  float* O = (float*)d_out;
  (void)in_sizes; (void)n_in; (void)out_size;

  const size_t needed = (size_t)B_ * NT * KT_F16 * 2 * 2;  // pk + pv = 64MB
  if (ws_size >= needed) {
    f16* pk = (f16*)d_ws;
    f16* pv = pk + (size_t)B_ * NT * KT_F16;
    pack_k<<<dim3(B_ * NT * 8), dim3(256), 0, stream>>>(K, pk);
    pack_v<<<dim3(B_ * NT), dim3(256), 0, stream>>>(V, pv);
    fattn<<<dim3(B_ * (N_ / NBLK)), dim3(512), 0, stream>>>(Q, pk, pv, O);
  } else {
    fattn_fb<<<dim3(B_ * (N_ / NBLK)), dim3(512), 0, stream>>>(Q, K, V, O);
  }
}